// Round 4
// baseline (278.650 us; speedup 1.0000x reference)
//
#include <hip/hip_runtime.h>
#include <hip/hip_fp16.h>

// AudioStructuralAnalyzer fused kernel, round 4.
// vs round 3:
//  - persistent blocks (1280 = 5/CU) + atomic work-stealing from d_ws counter:
//    no resident-block turnover; grid-balanced by construction
//  - register prefetch pipeline: c1's x loads issue during c0 compute; next
//    tile's c0 loads issue during c1 compute (tile grabbed one ahead)
//  - fatter phases: curv fused with j0-vertical; u-vertical into E2;
//    x^2-vertical into E3 (dest = dead P0). 15 barriers/tile (was 18)
//  - packed v_pk f16 sobel in the curv phase (~18 VALU/pixel, was ~45)

#define F_DIM 256
#define T_DIM 2048
#define B_DIM 8
#define C_DIM 2
#define TILE  32

#define XROWS 40          // x tile: halo 4
#define XS    42
#define UROWS 38          // (ux,uy): halo 3
#define US    38
#define FROWS 36          // field tiles: halo 2
#define FS    36
#define FH2   18          // FS/2 uint2 pairs per row
#define EPSF  1e-10f

#define NT_TILES (B_DIM * (F_DIM/TILE) * (T_DIM/TILE))   // 4096
#define NBLOCKS  1280                                     // 5 blocks/CU * 256 CU

static __device__ __forceinline__ __half2 pack_h2(float a, float b) {
    auto v = __builtin_amdgcn_cvt_pkrtz(a, b);   // v_cvt_pkrtz_f16_f32
    return *(__half2*)&v;
}
static __device__ __forceinline__ float clamp01(float x) {
    return fminf(fmaxf(x, 0.f), 1.f);
}

__global__ void zero_counter(int* p) { *p = 0; }

__global__ __launch_bounds__(256, 4)
void audio_struct_fused(const float* __restrict__ x_in,
                        const float* __restrict__ gk_in,
                        float* __restrict__ out,
                        int* __restrict__ counter)
{
    __shared__ __align__(16) float   s_x [XROWS*XS];    // 6720 B
    __shared__ __align__(16) __half2 s_u [UROWS*US];    // 5776 B (ux,uy)
    __shared__ __align__(16) __half2 s_P0[FROWS*FS];    // 5184 B (trace,diff) / x2-vert f32
    __shared__ __align__(16) __half2 s_P1[FROWS*FS];    // 5184 B (sxy,tin) / u-vert
    __shared__ __align__(16) __half2 s_P2[FROWS*FS];    // 5184 B (sf,cv)
    __shared__ __align__(16) float   s_tmp[TILE*FS];    // 4608 B ping-pong
    __shared__ int s_next;

    const int tx  = threadIdx.x;          // 0..31 (time)
    const int ty  = threadIdx.y;          // 0..7  (freq)
    const int tid = ty * 32 + tx;

    // 1D gaussian = normalized middle row of the separable 5x5 kernel
    float r0 = gk_in[10], r1 = gk_in[11], r2 = gk_in[12], r3 = gk_in[13], r4 = gk_in[14];
    float winv = __builtin_amdgcn_rcpf(r0 + r1 + r2 + r3 + r4);
    const float w[5] = {r0*winv, r1*winv, r2*winv, r3*winv, r4*winv};
    const __half2 wh2[5] = {pack_h2(w[0],w[0]), pack_h2(w[1],w[1]), pack_h2(w[2],w[2]),
                            pack_h2(w[3],w[3]), pack_h2(w[4],w[4])};
    const __half2 two_h2 = pack_h2(2.f, 2.f);

    // masked register prefetch of tile (tl, channel c) -> pre[4] (float2 each)
    auto prefetch = [&](int tl, int c, float2* pre) {
        int bb = tl >> 9, rm = tl & 511;
        int ff0 = (rm >> 6) << 5, tt0 = (rm & 63) << 5;
        const float* xp = x_in + (size_t)(bb * C_DIM + c) * F_DIM * T_DIM;
        bool ok = (tl < NT_TILES);
        #pragma unroll
        for (int k = 0; k < 4; ++k) {
            int idx = tid + 256 * k;
            int r = idx / 20, c2 = idx % 20;
            int gf = ff0 + r - 4, gt = tt0 + c2 * 2 - 4;
            float2 v = make_float2(0.f, 0.f);
            if (ok && idx < 800 &&
                (unsigned)gf < (unsigned)F_DIM && (unsigned)gt < (unsigned)T_DIM)
                v = *(const float2*)(xp + (size_t)gf * T_DIM + gt);
            pre[k] = v;
        }
    };

    // vertical 5-tap pass on packed pair buffers (uint2 = 4 halves per item)
    auto vpass_pair = [&](const __half2* src, __half2* dst) {
        const uint2* s = (const uint2*)src;
        uint2* d = (uint2*)dst;
        for (int idx = tid; idx < TILE * FH2; idx += 256) {
            __half2 a0 = pack_h2(0.f, 0.f), a1 = a0;
            #pragma unroll
            for (int i = 0; i < 5; ++i) {
                uint2 v = s[idx + i * FH2];
                a0 = __hfma2(wh2[i], *(const __half2*)&v.x, a0);
                a1 = __hfma2(wh2[i], *(const __half2*)&v.y, a1);
            }
            uint2 o; o.x = *(const unsigned*)&a0; o.y = *(const unsigned*)&a1;
            d[idx] = o;
        }
    };

    // ---- prologue: grab first tile, prefetch its channel 0 ----
    if (tid == 0) s_next = atomicAdd(counter, 1);
    __syncthreads();
    int tile = s_next;
    float2 pre[4];
    prefetch(tile, 0, pre);

    while (tile < NT_TILES) {
        const int b   = tile >> 9;
        const int rem = tile & 511;
        const int f0  = (rem >> 6) << 5;
        const int t0  = (rem & 63) << 5;
        int tile_next = tile;

        float acc[6][4];
        #pragma unroll
        for (int k = 0; k < 6; ++k)
            #pragma unroll
            for (int s = 0; s < 4; ++s) acc[k][s] = 0.0f;

        for (int c = 0; c < C_DIM; ++c) {
            __syncthreads();   // protects s_x & all LDS reuse from previous phase set

            // ---- Phase A: spill prefetched regs -> s_x ----
            #pragma unroll
            for (int k = 0; k < 4; ++k) {
                int idx = tid + 256 * k;
                if (idx < 800) {
                    int r = idx / 20, c2 = idx % 20;
                    *(float2*)&s_x[r * XS + c2 * 2] = pre[k];
                }
            }
            if (c == 0) {
                prefetch(tile, 1, pre);               // c1 loads fly during c0 compute
            } else if (tid == 0) {
                s_next = atomicAdd(counter, 1);       // grab next tile one ahead
            }
            __syncthreads();
            if (c == 1) {
                tile_next = s_next;
                prefetch(tile_next, 0, pre);          // next tile's c0 loads in flight
            }

            // ---- Phase B: (ux,uy) on 38x38; packed fields on 36x36 ----
            for (int idx = tid; idx < UROWS * UROWS; idx += 256) {
                int r = idx / UROWS, cc = idx % UROWS;
                int gfr = f0 + r - 3, gtc = t0 + cc - 3;
                float ux = 0.f, uy = 0.f, trp = 0.f, dfp = 0.f, sxy = 0.f,
                      tin = 0.f, sf = 0.f;
                if ((unsigned)gfr < (unsigned)F_DIM && (unsigned)gtc < (unsigned)T_DIM) {
                    const float* xc = &s_x[(r + 1) * XS + (cc + 1)];
                    float x00 = xc[-XS-1], x01 = xc[-XS], x02 = xc[-XS+1];
                    float x10 = xc[-1],                   x12 = xc[1];
                    float x20 = xc[XS-1],  x21 = xc[XS],  x22 = xc[XS+1];
                    float gfv = ((x20 + 2.f*x21 + x22) - (x00 + 2.f*x01 + x02)) * 0.125f;
                    float gtv = ((x02 + 2.f*x12 + x22) - (x00 + 2.f*x10 + x20)) * 0.125f;
                    float gte = gtv + EPSF;
                    float rh  = __builtin_amdgcn_rsqf(gfv * gfv + gte * gte);
                    ux = gte * rh;
                    uy = gfv * rh;
                    float mag = __builtin_amdgcn_sqrtf(gfv * gfv + gtv * gtv + EPSF);
                    float vx = mag * ux, vy = mag * uy;
                    trp = vx * vx + vy * vy;
                    dfp = (vx - vy) * (vx + vy);
                    sxy = vx * vy;
                    tin = __builtin_amdgcn_rcpf(1.0f + fabsf(gtv));
                    sf  = fabsf(gfv);
                }
                s_u[r * US + cc] = pack_h2(ux, uy);
                if (r >= 1 && r < UROWS - 1 && cc >= 1 && cc < UROWS - 1) {
                    int fi = (r - 1) * FS + (cc - 1);
                    s_P0[fi] = pack_h2(trp, dfp);
                    s_P1[fi] = pack_h2(sxy, tin);
                    s_P2[fi] = pack_h2(sf, 0.f);
                }
            }
            __syncthreads();

            // ---- E0: packed curv sobel -> s_P2.y ; j0 vertical P0 -> tmp ----
            __half2* tmp_h2 = (__half2*)s_tmp;
            for (int idx = tid; idx < FROWS * FROWS; idx += 256) {
                int r = idx / FROWS, cc = idx % FROWS;
                int gfr = f0 + r - 2, gtc = t0 + cc - 2;
                float cv = 0.0f;
                if ((unsigned)gfr < (unsigned)F_DIM && (unsigned)gtc < (unsigned)T_DIM) {
                    const __half2* up = &s_u[r * US + cc];
                    __half2 u00 = up[0],      u01 = up[1],       u02 = up[2];
                    __half2 u10 = up[US],                        u12 = up[US+2];
                    __half2 u20 = up[2*US],   u21 = up[2*US+1],  u22 = up[2*US+2];
                    __half2 vs0 = __hfma2(two_h2, u10, __hadd2(u00, u20));  // col sums
                    __half2 vs2 = __hfma2(two_h2, u12, __hadd2(u02, u22));
                    __half2 hs0 = __hfma2(two_h2, u01, __hadd2(u00, u02));  // row sums
                    __half2 hs2 = __hfma2(two_h2, u21, __hadd2(u20, u22));
                    __half2 dx  = __hsub2(vs2, vs0);   // 8*(dudx, dvdx)
                    __half2 dy  = __hsub2(hs2, hs0);   // 8*(dudy, dvdy)
                    __half2 sq  = __hfma2(dy, dy, __hmul2(dx, dx));
                    float ssum = __low2float(sq) + __high2float(sq);
                    cv = __builtin_amdgcn_sqrtf(ssum * 0.015625f + EPSF); // /64
                }
                ((__half*)s_P2)[2 * (r * FS + cc) + 1] = __float2half_rn(cv);
            }
            vpass_pair(s_P0, tmp_h2);
            __syncthreads();

            // ---- E1: j0 horizontal (f32) -> trace/diff regs ; j1 vertical P1 -> P0 ----
            float trace_s[4], diff_s[4];
            #pragma unroll
            for (int s = 0; s < 4; ++s) {
                int ry = ty + 8 * s;
                float a = 0.f, bv = 0.f;
                #pragma unroll
                for (int j = 0; j < 5; ++j) {
                    float2 v = __half22float2(tmp_h2[ry * FS + tx + j]);
                    a += w[j] * v.x; bv += w[j] * v.y;
                }
                trace_s[s] = a; diff_s[s] = bv;
            }
            vpass_pair(s_P1, s_P0);
            __syncthreads();

            // ---- E2: j1 horiz (entropy+temporal) ; j2 vert P2->tmp ; u-vert -> P1 ----
            #pragma unroll
            for (int s = 0; s < 4; ++s) {
                int ry = ty + 8 * s;
                __half2 a = pack_h2(0.f, 0.f);
                #pragma unroll
                for (int j = 0; j < 5; ++j)
                    a = __hfma2(wh2[j], s_P0[ry * FS + tx + j], a);
                float2 v = __half22float2(a);          // (vxy_s, tp)
                float trace = trace_s[s], diff = diff_s[s];
                float disc  = __builtin_amdgcn_sqrtf(
                                  fmaxf(diff * diff + 4.f * v.x * v.x, 0.f) + EPSF);
                float l1 = fmaxf(0.5f * (trace + disc), EPSF);
                float l2 = fmaxf(0.5f * (trace - disc), EPSF);
                float inv = __builtin_amdgcn_rcpf(l1 + l2 + EPSF);
                float p1 = l1 * inv, p2 = l2 * inv;
                float ent = -(p1 * __builtin_amdgcn_logf(p1 + EPSF)
                            + p2 * __builtin_amdgcn_logf(p2 + EPSF));
                acc[0][s] += 0.5f * clamp01(ent);
                acc[4][s] += 0.5f * clamp01(v.y);
            }
            vpass_pair(s_P2, tmp_h2);
            for (int idx = tid; idx < TILE * FS; idx += 256) {
                int r = idx / FS, cc = idx % FS;
                __half2 a = pack_h2(0.f, 0.f);
                #pragma unroll
                for (int i = 0; i < 5; ++i)
                    a = __hfma2(wh2[i], s_u[(r + i + 1) * US + (cc + 1)], a);
                s_P1[idx] = a;
            }
            __syncthreads();

            // ---- E3: j2 horiz (spectral+curvature) ; j3 horiz (alignment) ;
            //          x^2 vertical s_x -> (float*)P0 ----
            #pragma unroll
            for (int s = 0; s < 4; ++s) {
                int ry = ty + 8 * s;
                __half2 a = pack_h2(0.f, 0.f);
                #pragma unroll
                for (int j = 0; j < 5; ++j)
                    a = __hfma2(wh2[j], tmp_h2[ry * FS + tx + j], a);
                float2 v = __half22float2(a);          // (sp, cvs)
                acc[5][s] += 0.5f * clamp01(v.x);
                acc[2][s] += 0.5f * v.y;
                __half2 a2 = pack_h2(0.f, 0.f);
                #pragma unroll
                for (int j = 0; j < 5; ++j)
                    a2 = __hfma2(wh2[j], s_P1[ry * FS + tx + j], a2);
                float2 u = __half22float2(a2);         // (ua, va)
                acc[1][s] += 0.5f * clamp01(
                    __builtin_amdgcn_sqrtf(u.x * u.x + u.y * u.y + EPSF));
            }
            {
                float* xv2 = (float*)s_P0;
                for (int idx = tid; idx < TILE * FS; idx += 256) {
                    int r = idx / FS, cc = idx % FS;
                    float a = 0.f;
                    #pragma unroll
                    for (int i = 0; i < 5; ++i) {
                        float xv = s_x[(r + i + 2) * XS + (cc + 2)];
                        a += w[i] * xv * xv;
                    }
                    xv2[idx] = a;
                }
            }
            __syncthreads();

            // ---- E4: j4 horizontal (le) + harmonic epilogue ----
            {
                const float* xv2 = (const float*)s_P0;
                #pragma unroll
                for (int s = 0; s < 4; ++s) {
                    int ry = ty + 8 * s;
                    float le = 0.f;
                    #pragma unroll
                    for (int j = 0; j < 5; ++j)
                        le += w[j] * xv2[ry * FS + tx + j];
                    float xm  = s_x[(ry + 1) * XS + tx + 4];
                    float x0v = s_x[(ry + 4) * XS + tx + 4];
                    float xpv = s_x[(ry + 7) * XS + tx + 4];
                    float harm = fabsf(2.f * x0v - xm - xpv);
                    acc[3][s] += 0.5f * clamp01(harm * __builtin_amdgcn_rcpf(le + EPSF));
                }
            }
            // channel/tile-top __syncthreads() protects reuse
        }

        // ---- write 6 output planes for this tile, coalesced ----
        const size_t plane = (size_t)B_DIM * F_DIM * T_DIM;
        const size_t base  = (size_t)b * F_DIM * T_DIM + (size_t)f0 * T_DIM + t0 + tx;
        #pragma unroll
        for (int k = 0; k < 6; ++k)
            #pragma unroll
            for (int s = 0; s < 4; ++s)
                out[k * plane + base + (size_t)(ty + 8 * s) * T_DIM] = acc[k][s];

        tile = tile_next;
    }
}

extern "C" void kernel_launch(void* const* d_in, const int* in_sizes, int n_in,
                              void* d_out, int out_size, void* d_ws, size_t ws_size,
                              hipStream_t stream) {
    const float* x  = (const float*)d_in[0];
    const float* gk = (const float*)d_in[1];
    float* out = (float*)d_out;
    int* counter = (int*)d_ws;
    zero_counter<<<1, 1, 0, stream>>>(counter);
    dim3 block(32, 8);                              // 256 threads = 4 waves
    audio_struct_fused<<<NBLOCKS, block, 0, stream>>>(x, gk, out, counter);
}

// Round 5
// 257.923 us; speedup vs baseline: 1.0804x; 1.0804x over previous
//
#include <hip/hip_runtime.h>
#include <hip/hip_fp16.h>

// AudioStructuralAnalyzer fused kernel, round 5.
// vs round 4: REVERT work-stealing/persistent blocks (they doubled HBM traffic
// by destroying static-dispatch L2/L3 locality: FETCH 63->160MB, WRITE 142->244MB).
// KEEP the orthogonal r4 wins:
//  - packed v_pk f16 sobel in curv phase
//  - fused E0..E4 phases (7 barriers/channel)
//  - register prefetch of channel 1 issued during channel 0's Phase A
// Static grid dim3(64,8,8) as in r2/r3 (the good-locality configuration).

#define F_DIM 256
#define T_DIM 2048
#define B_DIM 8
#define C_DIM 2
#define TILE  32

#define XROWS 40          // x tile: halo 4
#define XS    42
#define UROWS 38          // (ux,uy): halo 3
#define US    38
#define FROWS 36          // field tiles: halo 2
#define FS    36
#define FH2   18          // FS/2 uint2 pairs per row
#define EPSF  1e-10f

static __device__ __forceinline__ __half2 pack_h2(float a, float b) {
    auto v = __builtin_amdgcn_cvt_pkrtz(a, b);   // v_cvt_pkrtz_f16_f32
    return *(__half2*)&v;
}
static __device__ __forceinline__ float clamp01(float x) {
    return fminf(fmaxf(x, 0.f), 1.f);
}

__global__ __launch_bounds__(256, 4)
void audio_struct_fused(const float* __restrict__ x_in,
                        const float* __restrict__ gk_in,
                        float* __restrict__ out)
{
    __shared__ __align__(16) float   s_x [XROWS*XS];    // 6720 B
    __shared__ __align__(16) __half2 s_u [UROWS*US];    // 5776 B (ux,uy)
    __shared__ __align__(16) __half2 s_P0[FROWS*FS];    // 5184 B (trace,diff) / x2-vert f32
    __shared__ __align__(16) __half2 s_P1[FROWS*FS];    // 5184 B (sxy,tin) / u-vert
    __shared__ __align__(16) __half2 s_P2[FROWS*FS];    // 5184 B (sf,cv)
    __shared__ __align__(16) float   s_tmp[TILE*FS];    // 4608 B ping-pong

    const int tx  = threadIdx.x;          // 0..31 (time)
    const int ty  = threadIdx.y;          // 0..7  (freq)
    const int tid = ty * 32 + tx;
    const int t0  = blockIdx.x * TILE;
    const int f0  = blockIdx.y * TILE;
    const int b   = blockIdx.z;

    // 1D gaussian = normalized middle row of the separable 5x5 kernel
    float r0 = gk_in[10], r1 = gk_in[11], r2 = gk_in[12], r3 = gk_in[13], r4 = gk_in[14];
    float winv = __builtin_amdgcn_rcpf(r0 + r1 + r2 + r3 + r4);
    const float w[5] = {r0*winv, r1*winv, r2*winv, r3*winv, r4*winv};
    const __half2 wh2[5] = {pack_h2(w[0],w[0]), pack_h2(w[1],w[1]), pack_h2(w[2],w[2]),
                            pack_h2(w[3],w[3]), pack_h2(w[4],w[4])};
    const __half2 two_h2 = pack_h2(2.f, 2.f);

    // masked register prefetch of channel c's x tile -> pre[4] (float2 each)
    auto prefetch = [&](int c, float2* pre) {
        const float* xp = x_in + (size_t)(b * C_DIM + c) * F_DIM * T_DIM;
        #pragma unroll
        for (int k = 0; k < 4; ++k) {
            int idx = tid + 256 * k;
            int r = idx / 20, c2 = idx % 20;
            int gf = f0 + r - 4, gt = t0 + c2 * 2 - 4;
            float2 v = make_float2(0.f, 0.f);
            if (idx < 800 &&
                (unsigned)gf < (unsigned)F_DIM && (unsigned)gt < (unsigned)T_DIM)
                v = *(const float2*)(xp + (size_t)gf * T_DIM + gt);
            pre[k] = v;
        }
    };

    // vertical 5-tap pass on packed pair buffers (uint2 = 4 halves per item)
    auto vpass_pair = [&](const __half2* src, __half2* dst) {
        const uint2* s = (const uint2*)src;
        uint2* d = (uint2*)dst;
        for (int idx = tid; idx < TILE * FH2; idx += 256) {
            __half2 a0 = pack_h2(0.f, 0.f), a1 = a0;
            #pragma unroll
            for (int i = 0; i < 5; ++i) {
                uint2 v = s[idx + i * FH2];
                a0 = __hfma2(wh2[i], *(const __half2*)&v.x, a0);
                a1 = __hfma2(wh2[i], *(const __half2*)&v.y, a1);
            }
            uint2 o; o.x = *(const unsigned*)&a0; o.y = *(const unsigned*)&a1;
            d[idx] = o;
        }
    };

    float acc[6][4];
    #pragma unroll
    for (int k = 0; k < 6; ++k)
        #pragma unroll
        for (int s = 0; s < 4; ++s) acc[k][s] = 0.0f;

    // prologue: issue channel-0 loads immediately
    float2 pre[4];
    prefetch(0, pre);

    for (int c = 0; c < C_DIM; ++c) {
        __syncthreads();   // protects s_x & all LDS reuse from previous phase set

        // ---- Phase A: spill prefetched regs -> s_x; issue c1 loads during c0 ----
        #pragma unroll
        for (int k = 0; k < 4; ++k) {
            int idx = tid + 256 * k;
            if (idx < 800) {
                int r = idx / 20, c2 = idx % 20;
                *(float2*)&s_x[r * XS + c2 * 2] = pre[k];
            }
        }
        if (c == 0) prefetch(1, pre);   // c1 loads in flight across all c0 phases
        __syncthreads();

        // ---- Phase B: (ux,uy) on 38x38; packed fields on 36x36 ----
        for (int idx = tid; idx < UROWS * UROWS; idx += 256) {
            int r = idx / UROWS, cc = idx % UROWS;
            int gfr = f0 + r - 3, gtc = t0 + cc - 3;
            float ux = 0.f, uy = 0.f, trp = 0.f, dfp = 0.f, sxy = 0.f,
                  tin = 0.f, sf = 0.f;
            if ((unsigned)gfr < (unsigned)F_DIM && (unsigned)gtc < (unsigned)T_DIM) {
                const float* xc = &s_x[(r + 1) * XS + (cc + 1)];
                float x00 = xc[-XS-1], x01 = xc[-XS], x02 = xc[-XS+1];
                float x10 = xc[-1],                   x12 = xc[1];
                float x20 = xc[XS-1],  x21 = xc[XS],  x22 = xc[XS+1];
                float gfv = ((x20 + 2.f*x21 + x22) - (x00 + 2.f*x01 + x02)) * 0.125f;
                float gtv = ((x02 + 2.f*x12 + x22) - (x00 + 2.f*x10 + x20)) * 0.125f;
                float gte = gtv + EPSF;
                float rh  = __builtin_amdgcn_rsqf(gfv * gfv + gte * gte);
                ux = gte * rh;
                uy = gfv * rh;
                float mag = __builtin_amdgcn_sqrtf(gfv * gfv + gtv * gtv + EPSF);
                float vx = mag * ux, vy = mag * uy;
                trp = vx * vx + vy * vy;               // sxx+syy
                dfp = (vx - vy) * (vx + vy);           // sxx-syy pre-quantization
                sxy = vx * vy;
                tin = __builtin_amdgcn_rcpf(1.0f + fabsf(gtv));
                sf  = fabsf(gfv);
            }
            s_u[r * US + cc] = pack_h2(ux, uy);
            if (r >= 1 && r < UROWS - 1 && cc >= 1 && cc < UROWS - 1) {
                int fi = (r - 1) * FS + (cc - 1);
                s_P0[fi] = pack_h2(trp, dfp);
                s_P1[fi] = pack_h2(sxy, tin);
                s_P2[fi] = pack_h2(sf, 0.f);
            }
        }
        __syncthreads();

        // ---- E0: packed curv sobel -> s_P2.y ; j0 vertical P0 -> tmp ----
        __half2* tmp_h2 = (__half2*)s_tmp;
        for (int idx = tid; idx < FROWS * FROWS; idx += 256) {
            int r = idx / FROWS, cc = idx % FROWS;
            int gfr = f0 + r - 2, gtc = t0 + cc - 2;
            float cv = 0.0f;
            if ((unsigned)gfr < (unsigned)F_DIM && (unsigned)gtc < (unsigned)T_DIM) {
                const __half2* up = &s_u[r * US + cc];
                __half2 u00 = up[0],      u01 = up[1],       u02 = up[2];
                __half2 u10 = up[US],                        u12 = up[US+2];
                __half2 u20 = up[2*US],   u21 = up[2*US+1],  u22 = up[2*US+2];
                __half2 vs0 = __hfma2(two_h2, u10, __hadd2(u00, u20));  // col sums
                __half2 vs2 = __hfma2(two_h2, u12, __hadd2(u02, u22));
                __half2 hs0 = __hfma2(two_h2, u01, __hadd2(u00, u02));  // row sums
                __half2 hs2 = __hfma2(two_h2, u21, __hadd2(u20, u22));
                __half2 dx  = __hsub2(vs2, vs0);   // 8*(dudx, dvdx)
                __half2 dy  = __hsub2(hs2, hs0);   // 8*(dudy, dvdy)
                __half2 sq  = __hfma2(dy, dy, __hmul2(dx, dx));
                float ssum = __low2float(sq) + __high2float(sq);
                cv = __builtin_amdgcn_sqrtf(ssum * 0.015625f + EPSF); // /64
            }
            ((__half*)s_P2)[2 * (r * FS + cc) + 1] = __float2half_rn(cv);
        }
        vpass_pair(s_P0, tmp_h2);
        __syncthreads();

        // ---- E1: j0 horizontal (f32) -> trace/diff regs ; j1 vertical P1 -> P0 ----
        float trace_s[4], diff_s[4];
        #pragma unroll
        for (int s = 0; s < 4; ++s) {
            int ry = ty + 8 * s;
            float a = 0.f, bv = 0.f;
            #pragma unroll
            for (int j = 0; j < 5; ++j) {
                float2 v = __half22float2(tmp_h2[ry * FS + tx + j]);
                a += w[j] * v.x; bv += w[j] * v.y;
            }
            trace_s[s] = a; diff_s[s] = bv;
        }
        vpass_pair(s_P1, s_P0);
        __syncthreads();

        // ---- E2: j1 horiz (entropy+temporal) ; j2 vert P2->tmp ; u-vert -> P1 ----
        #pragma unroll
        for (int s = 0; s < 4; ++s) {
            int ry = ty + 8 * s;
            __half2 a = pack_h2(0.f, 0.f);
            #pragma unroll
            for (int j = 0; j < 5; ++j)
                a = __hfma2(wh2[j], s_P0[ry * FS + tx + j], a);
            float2 v = __half22float2(a);          // (vxy_s, tp)
            float trace = trace_s[s], diff = diff_s[s];
            float disc  = __builtin_amdgcn_sqrtf(
                              fmaxf(diff * diff + 4.f * v.x * v.x, 0.f) + EPSF);
            float l1 = fmaxf(0.5f * (trace + disc), EPSF);
            float l2 = fmaxf(0.5f * (trace - disc), EPSF);
            float inv = __builtin_amdgcn_rcpf(l1 + l2 + EPSF);
            float p1 = l1 * inv, p2 = l2 * inv;
            float ent = -(p1 * __builtin_amdgcn_logf(p1 + EPSF)
                        + p2 * __builtin_amdgcn_logf(p2 + EPSF));
            acc[0][s] += 0.5f * clamp01(ent);
            acc[4][s] += 0.5f * clamp01(v.y);
        }
        vpass_pair(s_P2, tmp_h2);
        for (int idx = tid; idx < TILE * FS; idx += 256) {
            int r = idx / FS, cc = idx % FS;
            __half2 a = pack_h2(0.f, 0.f);
            #pragma unroll
            for (int i = 0; i < 5; ++i)
                a = __hfma2(wh2[i], s_u[(r + i + 1) * US + (cc + 1)], a);
            s_P1[idx] = a;
        }
        __syncthreads();

        // ---- E3: j2 horiz (spectral+curvature) ; j3 horiz (alignment) ;
        //          x^2 vertical s_x -> (float*)P0 ----
        #pragma unroll
        for (int s = 0; s < 4; ++s) {
            int ry = ty + 8 * s;
            __half2 a = pack_h2(0.f, 0.f);
            #pragma unroll
            for (int j = 0; j < 5; ++j)
                a = __hfma2(wh2[j], tmp_h2[ry * FS + tx + j], a);
            float2 v = __half22float2(a);          // (sp, cvs)
            acc[5][s] += 0.5f * clamp01(v.x);
            acc[2][s] += 0.5f * v.y;
            __half2 a2 = pack_h2(0.f, 0.f);
            #pragma unroll
            for (int j = 0; j < 5; ++j)
                a2 = __hfma2(wh2[j], s_P1[ry * FS + tx + j], a2);
            float2 u = __half22float2(a2);         // (ua, va)
            acc[1][s] += 0.5f * clamp01(
                __builtin_amdgcn_sqrtf(u.x * u.x + u.y * u.y + EPSF));
        }
        {
            float* xv2 = (float*)s_P0;
            for (int idx = tid; idx < TILE * FS; idx += 256) {
                int r = idx / FS, cc = idx % FS;
                float a = 0.f;
                #pragma unroll
                for (int i = 0; i < 5; ++i) {
                    float xv = s_x[(r + i + 2) * XS + (cc + 2)];
                    a += w[i] * xv * xv;
                }
                xv2[idx] = a;
            }
        }
        __syncthreads();

        // ---- E4: j4 horizontal (le) + harmonic epilogue ----
        {
            const float* xv2 = (const float*)s_P0;
            #pragma unroll
            for (int s = 0; s < 4; ++s) {
                int ry = ty + 8 * s;
                float le = 0.f;
                #pragma unroll
                for (int j = 0; j < 5; ++j)
                    le += w[j] * xv2[ry * FS + tx + j];
                float xm  = s_x[(ry + 1) * XS + tx + 4];
                float x0v = s_x[(ry + 4) * XS + tx + 4];
                float xpv = s_x[(ry + 7) * XS + tx + 4];
                float harm = fabsf(2.f * x0v - xm - xpv);
                acc[3][s] += 0.5f * clamp01(harm * __builtin_amdgcn_rcpf(le + EPSF));
            }
        }
        // loop-top __syncthreads() protects reuse for channel 1
    }

    // ---- write 6 output planes, coalesced ----
    const size_t plane = (size_t)B_DIM * F_DIM * T_DIM;
    const size_t base  = (size_t)b * F_DIM * T_DIM + (size_t)f0 * T_DIM + t0 + tx;
    #pragma unroll
    for (int k = 0; k < 6; ++k)
        #pragma unroll
        for (int s = 0; s < 4; ++s)
            out[k * plane + base + (size_t)(ty + 8 * s) * T_DIM] = acc[k][s];
}

extern "C" void kernel_launch(void* const* d_in, const int* in_sizes, int n_in,
                              void* d_out, int out_size, void* d_ws, size_t ws_size,
                              hipStream_t stream) {
    const float* x  = (const float*)d_in[0];
    const float* gk = (const float*)d_in[1];
    float* out = (float*)d_out;
    dim3 grid(T_DIM / TILE, F_DIM / TILE, B_DIM);   // 64 x 8 x 8 = 4096 blocks
    dim3 block(32, 8);                              // 256 threads = 4 waves
    audio_struct_fused<<<grid, block, 0, stream>>>(x, gk, out);
}